// Round 9
// baseline (520.014 us; speedup 1.0000x reference)
//
#include <hip/hip_runtime.h>
#include <math.h>

#define TIN   32
#define THID  32
#define TOUT  32
#define TEDGE 8
#define CHUNK 4        // nodes per wave in fused kernel
#define MAXDEG 64      // padded slots per node (P(Poisson(32)>64) ~ 1e-8)

typedef __attribute__((ext_vector_type(8))) short bf16x8;
typedef __attribute__((ext_vector_type(4))) float f32x4;

#define MFMA16(a, b, c) __builtin_amdgcn_mfma_f32_16x16x32_bf16((a), (b), (c), 0, 0, 0)

__device__ __forceinline__ unsigned int cvtpk(float lo, float hi) {
    unsigned int r;
    asm("v_cvt_pk_bf16_f32 %0, %1, %2" : "=v"(r) : "v"(lo), "v"(hi));
    return r;
}

__device__ __forceinline__ float silu_f(float x) {
    float e = __expf(-x);
    return x * __builtin_amdgcn_rcpf(1.0f + e);
}

union U4F { unsigned int u[4]; bf16x8 v; };
union U4Q { uint4 q; bf16x8 v; };

__device__ __forceinline__ bf16x8 pack8bf(const float* f) {
    U4F t;
    t.u[0] = cvtpk(f[0], f[1]);
    t.u[1] = cvtpk(f[2], f[3]);
    t.u[2] = cvtpk(f[4], f[5]);
    t.u[3] = cvtpk(f[6], f[7]);
    return t.v;
}

__device__ __forceinline__ bf16x8 load_wT(const float* __restrict__ W, int kbase, int ch, int Kreal) {
    float f[8];
    #pragma unroll
    for (int e = 0; e < 8; ++e) {
        int k = kbase + e;
        f[e] = (k < Kreal) ? W[k * 32 + ch] : 0.0f;
    }
    return pack8bf(f);
}

// Layer-1 third K-block. B-side mapping: g0 slots = {radial, 1.0(bias), 0..};
// g1 slots = {ef0..ef7}; g2,g3 = 0.
// So A: g0 rows = {We1 row 64 (radial), be1}; g1 rows = We1 rows 65..72.
__device__ __forceinline__ bf16x8 load_wA12(const float* __restrict__ We1,
                                            const float* __restrict__ be1, int g, int ch) {
    float f[8];
    #pragma unroll
    for (int e = 0; e < 8; ++e) f[e] = 0.0f;
    if (g == 0) { f[0] = We1[64 * 32 + ch]; f[1] = be1[ch]; }
    else if (g == 1) {
        #pragma unroll
        for (int e = 0; e < 8; ++e) f[e] = We1[(65 + e) * 32 + ch];
    }
    return pack8bf(f);
}

// ---------------- phase 0a: node_feat f32 -> bf16 rows ----------------
__global__ __launch_bounds__(256) void conv_node_kernel(
    const float* __restrict__ nf, unsigned int* __restrict__ nb, int total /* N*16 */)
{
    int i = blockIdx.x * 256 + threadIdx.x;
    int stride = gridDim.x * 256;
    for (; i < total; i += stride) {
        float2 v = reinterpret_cast<const float2*>(nf)[i];
        nb[i] = cvtpk(v.x, v.y);
    }
}

// ---------------- phase 0b: coord [N,3] -> padded float4 ----------------
__global__ __launch_bounds__(256) void conv_coord_kernel(
    const float* __restrict__ c, float4* __restrict__ c4, int N)
{
    int i = blockIdx.x * 256 + threadIdx.x;
    int stride = gridDim.x * 256;
    for (; i < N; i += stride) {
        float4 v;
        v.x = c[3*(size_t)i+0]; v.y = c[3*(size_t)i+1]; v.z = c[3*(size_t)i+2]; v.w = 0.0f;
        c4[i] = v;
    }
}

// ---------------- phase 1: rank + scatter edge data (no geometry, no gathers) ----------------
__global__ __launch_bounds__(256) void record_rank_kernel(
    const int* __restrict__ src,
    const int* __restrict__ dst,
    const float* __restrict__ edge_feat,
    int* __restrict__ cnt,          // [N+1]
    int* __restrict__ srcA,         // [N*MAXDEG]
    uint4* __restrict__ efA,        // [N*MAXDEG]
    int E)
{
    int e = blockIdx.x * 256 + threadIdx.x;
    if (e >= E) return;
    int d = dst[e];
    int rank = atomicAdd(&cnt[d], 1);
    if (rank >= MAXDEG) return;     // overflow handled by ovf_fix_node (dead path)
    int slot = (d << 6) + rank;     // MAXDEG == 64

    srcA[slot] = src[e];
    const float4* ep = reinterpret_cast<const float4*>(edge_feat + (size_t)e * TEDGE);
    float4 e0 = ep[0], e1 = ep[1];
    uint4 ef;
    ef.x = cvtpk(e0.x, e0.y);
    ef.y = cvtpk(e0.z, e0.w);
    ef.z = cvtpk(e1.x, e1.y);
    ef.w = cvtpk(e1.z, e1.w);
    efA[slot] = ef;
}

// ---------------- phase 2: FUSED edge MLP + geometry + segment aggregation ----------------
__global__ __launch_bounds__(256) void egnn_fused(
    const uint4* __restrict__ node_bf4,   // [N][4] uint4 (64B bf16 rows)
    const float4* __restrict__ coord4,    // [N]
    const int*  __restrict__ srcA,        // [N*MAXDEG]
    const uint4* __restrict__ efA,        // [N*MAXDEG]
    const int*  __restrict__ cnt,         // [N] true degrees
    const float* __restrict__ We1,
    const float* __restrict__ be1,
    const float* __restrict__ We2,
    const float* __restrict__ be2,
    const float* __restrict__ Wc1,
    const float* __restrict__ bc1,
    const float* __restrict__ Wc2,
    float4* __restrict__ h_acc4,          // [N][8] float4
    float4* __restrict__ xd4,             // [N] {x0,x1,x2,deg}
    int N)
{
    const int lane = threadIdx.x & 63;
    const int wid  = threadIdx.x >> 6;
    const int r    = lane & 15;
    const int g    = lane >> 4;

    bf16x8 A10[2], A11[2], A12[2], A2[2], A3[2];
    A10[0] = load_wT(We1,      8*g, r,      73);
    A10[1] = load_wT(We1,      8*g, 16 + r, 73);
    A11[0] = load_wT(We1, 32 + 8*g, r,      73);
    A11[1] = load_wT(We1, 32 + 8*g, 16 + r, 73);
    A12[0] = load_wA12(We1, be1, g, r);
    A12[1] = load_wA12(We1, be1, g, 16 + r);
    A2[0] = load_wT(We2, 8*g, r, 32);      A2[1] = load_wT(We2, 8*g, 16 + r, 32);
    A3[0] = load_wT(Wc1, 8*g, r, 32);      A3[1] = load_wT(Wc1, 8*g, 16 + r, 32);

    float be2v[8], bc1v[8], wc2v[8];
    #pragma unroll
    for (int h = 0; h < 2; ++h)
        #pragma unroll
        for (int q = 0; q < 4; ++q) {
            int ch = 16*h + 4*g + q;
            be2v[4*h+q] = be2[ch];
            bc1v[4*h+q] = bc1[ch];
            wc2v[4*h+q] = Wc2[ch];
        }

    const bool Hhi = ((g >> 1) & 1) != 0;
    const int  s0L = 32 * (g & 1) + r;
    const int  s1L = s0L + 16;

    int c0n = (blockIdx.x * 4 + wid) * CHUNK;

    for (int n = c0n; n < c0n + CHUNK && n < N; ++n) {
        int deg = cnt[n];
        int len = deg < MAXDEG ? deg : MAXDEG;
        int segbase = n << 6;

        U4Q Bd; Bd.q = node_bf4[(size_t)n * 4 + g];
        float4 cd = coord4[n];

        // per-node dst-term of layer 1 (constant across the segment)
        f32x4 z4 = {0.f,0.f,0.f,0.f};
        f32x4 dst0 = MFMA16(A11[0], Bd.v, z4);
        f32x4 dst1 = MFMA16(A11[1], Bd.v, z4);

        float ha0[4] = {0.f,0.f,0.f,0.f}, ha1[4] = {0.f,0.f,0.f,0.f};
        float xa0 = 0.f, xa1 = 0.f, xa2 = 0.f;

        for (int t = 0; t < len; t += 16) {
            int idx = t + r;
            bool valid = idx < len;
            int slot = segbase + (valid ? idx : 0);

            int srcv = srcA[slot];                       // coalesced (dst-sorted)
            U4Q Bs; Bs.q = node_bf4[(size_t)srcv * 4 + g];

            float dx0 = 0.f, dx1 = 0.f, dx2 = 0.f;
            U4F Bk2;
            Bk2.u[0] = 0u; Bk2.u[1] = 0u; Bk2.u[2] = 0u; Bk2.u[3] = 0u;
            if (g == 0) {
                float4 cs = coord4[srcv];
                dx0 = cs.x - cd.x; dx1 = cs.y - cd.y; dx2 = cs.z - cd.z;
                float radial = dx0*dx0 + dx1*dx1 + dx2*dx2;
                float invn = __builtin_amdgcn_rcpf(sqrtf(radial) + 1e-30f);
                dx0 *= invn; dx1 *= invn; dx2 *= invn;
                Bk2.u[0] = cvtpk(radial, 1.0f);          // {radial, bias 1.0}
            } else if (g == 1) {
                uint4 ef = efA[slot];                     // coalesced
                Bk2.u[0] = ef.x; Bk2.u[1] = ef.y; Bk2.u[2] = ef.z; Bk2.u[3] = ef.w;
            }

            // ---- layer 1 (dst term pre-accumulated) ----
            f32x4 acc0 = dst0, acc1 = dst1;
            acc0 = MFMA16(A10[0], Bs.v,   acc0);
            acc0 = MFMA16(A12[0], Bk2.v,  acc0);
            acc1 = MFMA16(A10[1], Bs.v,   acc1);
            acc1 = MFMA16(A12[1], Bk2.v,  acc1);

            unsigned int pk0 = cvtpk(silu_f(acc0[0]), silu_f(acc0[1]));
            unsigned int pk1 = cvtpk(silu_f(acc0[2]), silu_f(acc0[3]));
            unsigned int pk2 = cvtpk(silu_f(acc1[0]), silu_f(acc1[1]));
            unsigned int pk3 = cvtpk(silu_f(acc1[2]), silu_f(acc1[3]));

            // ---- transpose a1 -> B2 ----
            unsigned int al0 = __shfl(pk0, s0L, 64), al1 = __shfl(pk1, s0L, 64);
            unsigned int ah0 = __shfl(pk2, s0L, 64), ah1 = __shfl(pk3, s0L, 64);
            unsigned int bl0 = __shfl(pk0, s1L, 64), bl1 = __shfl(pk1, s1L, 64);
            unsigned int bh0 = __shfl(pk2, s1L, 64), bh1 = __shfl(pk3, s1L, 64);
            U4F B2u;
            B2u.u[0] = Hhi ? ah0 : al0;  B2u.u[1] = Hhi ? ah1 : al1;
            B2u.u[2] = Hhi ? bh0 : bl0;  B2u.u[3] = Hhi ? bh1 : bl1;

            // ---- layer 2 ----
            f32x4 m0, m1;
            #pragma unroll
            for (int q = 0; q < 4; ++q) { m0[q] = be2v[q]; m1[q] = be2v[4+q]; }
            m0 = MFMA16(A2[0], B2u.v, m0);
            m1 = MFMA16(A2[1], B2u.v, m1);

            float vm = valid ? 1.0f : 0.0f;
            float s00 = silu_f(m0[0]) * vm, s01 = silu_f(m0[1]) * vm;
            float s02 = silu_f(m0[2]) * vm, s03 = silu_f(m0[3]) * vm;
            float s10 = silu_f(m1[0]) * vm, s11 = silu_f(m1[1]) * vm;
            float s12 = silu_f(m1[2]) * vm, s13 = silu_f(m1[3]) * vm;

            ha0[0] += s00; ha0[1] += s01; ha0[2] += s02; ha0[3] += s03;
            ha1[0] += s10; ha1[1] += s11; ha1[2] += s12; ha1[3] += s13;

            unsigned int mpk0 = cvtpk(s00, s01);
            unsigned int mpk1 = cvtpk(s02, s03);
            unsigned int mpk2 = cvtpk(s10, s11);
            unsigned int mpk3 = cvtpk(s12, s13);

            // ---- transpose msg -> B3 ----
            unsigned int cl0 = __shfl(mpk0, s0L, 64), cl1 = __shfl(mpk1, s0L, 64);
            unsigned int ch0 = __shfl(mpk2, s0L, 64), ch1 = __shfl(mpk3, s0L, 64);
            unsigned int dl0 = __shfl(mpk0, s1L, 64), dl1 = __shfl(mpk1, s1L, 64);
            unsigned int dh0 = __shfl(mpk2, s1L, 64), dh1 = __shfl(mpk3, s1L, 64);
            U4F B3u;
            B3u.u[0] = Hhi ? ch0 : cl0;  B3u.u[1] = Hhi ? ch1 : cl1;
            B3u.u[2] = Hhi ? dh0 : dl0;  B3u.u[3] = Hhi ? dh1 : dl1;

            // ---- layer 3: coord gate ----
            f32x4 c0, c1;
            #pragma unroll
            for (int q = 0; q < 4; ++q) { c0[q] = bc1v[q]; c1[q] = bc1v[4+q]; }
            c0 = MFMA16(A3[0], B3u.v, c0);
            c1 = MFMA16(A3[1], B3u.v, c1);

            float gp = 0.0f;
            #pragma unroll
            for (int q = 0; q < 4; ++q) {
                gp = fmaf(silu_f(c0[q]), wc2v[q],   gp);
                gp = fmaf(silu_f(c1[q]), wc2v[4+q], gp);
            }
            gp += __shfl_xor(gp, 16, 64);
            gp += __shfl_xor(gp, 32, 64);

            // x partials (dx f32, valid on g0 lanes; others accumulate zeros)
            xa0 = fmaf(gp * vm, dx0, xa0);
            xa1 = fmaf(gp * vm, dx1, xa1);
            xa2 = fmaf(gp * vm, dx2, xa2);
        }

        #pragma unroll
        for (int off = 1; off < 16; off <<= 1) {
            #pragma unroll
            for (int q = 0; q < 4; ++q) {
                ha0[q] += __shfl_xor(ha0[q], off, 64);
                ha1[q] += __shfl_xor(ha1[q], off, 64);
            }
            xa0 += __shfl_xor(xa0, off, 64);
            xa1 += __shfl_xor(xa1, off, 64);
            xa2 += __shfl_xor(xa2, off, 64);
        }

        if (r == 0) {
            float4 v0; v0.x = ha0[0]; v0.y = ha0[1]; v0.z = ha0[2]; v0.w = ha0[3];
            float4 v1; v1.x = ha1[0]; v1.y = ha1[1]; v1.z = ha1[2]; v1.w = ha1[3];
            h_acc4[(size_t)n * 8 + g]     = v0;
            h_acc4[(size_t)n * 8 + 4 + g] = v1;
            if (g == 0) {
                float4 xv; xv.x = xa0; xv.y = xa1; xv.z = xa2; xv.w = (float)deg;
                xd4[n] = xv;
            }
        }
    }
}

// ---------------- overflow fix-up: per-node check + exact scalar recompute ----------------
// Dead path for this data (P(deg>64) ~ 1e-8); kept for correctness on any input.
__global__ __launch_bounds__(256) void ovf_fix_node(
    const float* __restrict__ node_feat,
    const float* __restrict__ coord,
    const float* __restrict__ edge_feat,
    const int* __restrict__ src,
    const int* __restrict__ dst,
    const int* __restrict__ cnt,
    const float* __restrict__ We1,
    const float* __restrict__ be1,
    const float* __restrict__ We2,
    const float* __restrict__ be2,
    const float* __restrict__ Wc1,
    const float* __restrict__ bc1,
    const float* __restrict__ Wc2,
    float* __restrict__ h_acc,
    float4* __restrict__ xd4,
    int N, int E)
{
    int n = blockIdx.x * 256 + threadIdx.x;
    if (n >= N) return;
    if (cnt[n] <= MAXDEG) return;

    float hsum[THID];
    #pragma unroll
    for (int j = 0; j < THID; ++j) hsum[j] = 0.f;
    float xs0 = 0.f, xs1 = 0.f, xs2 = 0.f;
    int degc = 0;
    for (int ee = 0; ee < E; ++ee) {
        if (dst[ee] != n) continue;
        ++degc;
        int ss = src[ee];
        float dx0 = coord[3*(size_t)ss+0] - coord[3*(size_t)n+0];
        float dx1 = coord[3*(size_t)ss+1] - coord[3*(size_t)n+1];
        float dx2 = coord[3*(size_t)ss+2] - coord[3*(size_t)n+2];
        float radial = dx0*dx0 + dx1*dx1 + dx2*dx2;
        float invn = 1.0f / (sqrtf(radial) + 1e-30f);
        dx0 *= invn; dx1 *= invn; dx2 *= invn;
        float f[73];
        for (int k = 0; k < 32; ++k) f[k] = node_feat[(size_t)ss*TIN + k];
        for (int k = 0; k < 32; ++k) f[32+k] = node_feat[(size_t)n*TIN + k];
        f[64] = radial;
        for (int k = 0; k < 8; ++k) f[65+k] = edge_feat[(size_t)ee*TEDGE + k];
        float a1[THID];
        for (int j = 0; j < THID; ++j) a1[j] = be1[j];
        for (int k = 0; k < 73; ++k) {
            float fk = f[k];
            for (int j = 0; j < THID; ++j) a1[j] = fmaf(fk, We1[k*THID + j], a1[j]);
        }
        for (int j = 0; j < THID; ++j) a1[j] = silu_f(a1[j]);
        float msg[THID];
        for (int j = 0; j < THID; ++j) msg[j] = be2[j];
        for (int k = 0; k < THID; ++k) {
            float fk = a1[k];
            for (int j = 0; j < THID; ++j) msg[j] = fmaf(fk, We2[k*THID + j], msg[j]);
        }
        for (int j = 0; j < THID; ++j) msg[j] = silu_f(msg[j]);
        float c1[THID];
        for (int j = 0; j < THID; ++j) c1[j] = bc1[j];
        for (int k = 0; k < THID; ++k) {
            float fk = msg[k];
            for (int j = 0; j < THID; ++j) c1[j] = fmaf(fk, Wc1[k*THID + j], c1[j]);
        }
        float gate = 0.0f;
        for (int j = 0; j < THID; ++j) gate = fmaf(silu_f(c1[j]), Wc2[j], gate);
        for (int j = 0; j < THID; ++j) hsum[j] += msg[j];
        xs0 += gate * dx0; xs1 += gate * dx1; xs2 += gate * dx2;
    }
    for (int j = 0; j < THID; ++j) h_acc[(size_t)n * THID + j] = hsum[j];
    float4 xv; xv.x = xs0; xv.y = xs1; xv.z = xs2; xv.w = (float)degc;
    xd4[n] = xv;
}

// ---------------- fallback: atomic edge kernel (small-ws path) ----------------
__global__ __launch_bounds__(256) void egnn_edge_atomic(
    const float* __restrict__ node_feat,
    const float* __restrict__ coord,
    const float* __restrict__ edge_feat,
    const int*   __restrict__ src,
    const int*   __restrict__ dst,
    const float* __restrict__ We1,
    const float* __restrict__ be1,
    const float* __restrict__ We2,
    const float* __restrict__ be2,
    const float* __restrict__ Wc1,
    const float* __restrict__ bc1,
    const float* __restrict__ Wc2,
    float* __restrict__ h_acc,
    float* __restrict__ x_acc,   // [N][4] {x,y,z,deg}
    int E)
{
    int e = blockIdx.x * 256 + threadIdx.x;
    if (e >= E) return;
    int s = src[e];
    int d = dst[e];
    float dx0 = coord[3*(size_t)s+0] - coord[3*(size_t)d+0];
    float dx1 = coord[3*(size_t)s+1] - coord[3*(size_t)d+1];
    float dx2 = coord[3*(size_t)s+2] - coord[3*(size_t)d+2];
    float radial = dx0*dx0 + dx1*dx1 + dx2*dx2;
    float invn = 1.0f / (sqrtf(radial) + 1e-30f);
    dx0 *= invn; dx1 *= invn; dx2 *= invn;
    float f[73];
    #pragma unroll
    for (int i = 0; i < 32; ++i) f[i] = node_feat[(size_t)s*TIN + i];
    #pragma unroll
    for (int i = 0; i < 32; ++i) f[32+i] = node_feat[(size_t)d*TIN + i];
    f[64] = radial;
    #pragma unroll
    for (int i = 0; i < 8; ++i) f[65+i] = edge_feat[(size_t)e*TEDGE + i];
    float a1[THID];
    #pragma unroll
    for (int j = 0; j < THID; ++j) a1[j] = be1[j];
    for (int k = 0; k < 73; ++k) {
        float fk = f[k];
        #pragma unroll
        for (int j = 0; j < THID; ++j) a1[j] = fmaf(fk, We1[k*THID + j], a1[j]);
    }
    #pragma unroll
    for (int j = 0; j < THID; ++j) a1[j] = silu_f(a1[j]);
    float msg[THID];
    #pragma unroll
    for (int j = 0; j < THID; ++j) msg[j] = be2[j];
    for (int k = 0; k < THID; ++k) {
        float fk = a1[k];
        #pragma unroll
        for (int j = 0; j < THID; ++j) msg[j] = fmaf(fk, We2[k*THID + j], msg[j]);
    }
    #pragma unroll
    for (int j = 0; j < THID; ++j) msg[j] = silu_f(msg[j]);
    float c1[THID];
    #pragma unroll
    for (int j = 0; j < THID; ++j) c1[j] = bc1[j];
    for (int k = 0; k < THID; ++k) {
        float fk = msg[k];
        #pragma unroll
        for (int j = 0; j < THID; ++j) c1[j] = fmaf(fk, Wc1[k*THID + j], c1[j]);
    }
    float gate = 0.0f;
    #pragma unroll
    for (int j = 0; j < THID; ++j) gate = fmaf(silu_f(c1[j]), Wc2[j], gate);
    float* ha = h_acc + (size_t)d * THID;
    #pragma unroll
    for (int j = 0; j < THID; ++j) atomicAdd(ha + j, msg[j]);
    atomicAdd(x_acc + (size_t)d*4 + 0, gate * dx0);
    atomicAdd(x_acc + (size_t)d*4 + 1, gate * dx1);
    atomicAdd(x_acc + (size_t)d*4 + 2, gate * dx2);
    atomicAdd(x_acc + (size_t)d*4 + 3, 1.0f);
}

// ---------------- phase 3: node update ----------------
__global__ __launch_bounds__(256) void egnn_node(
    const float* __restrict__ node_feat,
    const float* __restrict__ coord,
    const float* __restrict__ Wn1,
    const float* __restrict__ bn1,
    const float* __restrict__ Wn2,
    const float* __restrict__ bn2,
    const float* __restrict__ h_acc,
    const float4* __restrict__ xd4,   // {x,y,z,deg}
    float* __restrict__ out_h,
    float* __restrict__ out_x,
    int N)
{
    int n = blockIdx.x * 256 + threadIdx.x;
    if (n >= N) return;

    float f2[2*TIN];
    {
        const float4* p = reinterpret_cast<const float4*>(node_feat + (size_t)n * TIN);
        #pragma unroll
        for (int i = 0; i < TIN/4; ++i) {
            float4 v = p[i];
            f2[4*i+0]=v.x; f2[4*i+1]=v.y; f2[4*i+2]=v.z; f2[4*i+3]=v.w;
        }
    }
    {
        const float4* p = reinterpret_cast<const float4*>(h_acc + (size_t)n * THID);
        #pragma unroll
        for (int i = 0; i < THID/4; ++i) {
            float4 v = p[i];
            f2[TIN+4*i+0]=v.x; f2[TIN+4*i+1]=v.y; f2[TIN+4*i+2]=v.z; f2[TIN+4*i+3]=v.w;
        }
    }

    float a[THID];
    #pragma unroll
    for (int j = 0; j < THID; ++j) a[j] = bn1[j];
    #pragma unroll
    for (int k = 0; k < 2*TIN; ++k) {
        float fk = f2[k];
        #pragma unroll
        for (int j = 0; j < THID; ++j) a[j] = fmaf(fk, Wn1[k*THID + j], a[j]);
    }
    #pragma unroll
    for (int j = 0; j < THID; ++j) a[j] = silu_f(a[j]);

    float h[TOUT];
    #pragma unroll
    for (int j = 0; j < TOUT; ++j) h[j] = bn2[j];
    #pragma unroll
    for (int k = 0; k < THID; ++k) {
        float fk = a[k];
        #pragma unroll
        for (int j = 0; j < TOUT; ++j) h[j] = fmaf(fk, Wn2[k*TOUT + j], h[j]);
    }

    float4* po = reinterpret_cast<float4*>(out_h + (size_t)n * TOUT);
    #pragma unroll
    for (int i = 0; i < TOUT/4; ++i) {
        float4 v; v.x=h[4*i+0]; v.y=h[4*i+1]; v.z=h[4*i+2]; v.w=h[4*i+3];
        po[i] = v;
    }

    float4 xv = xd4[n];
    float dg = fmaxf(xv.w, 1.0f);
    float inv = __builtin_amdgcn_rcpf(dg);
    out_x[(size_t)n*3+0] = coord[(size_t)n*3+0] + xv.x * inv;
    out_x[(size_t)n*3+1] = coord[(size_t)n*3+1] + xv.y * inv;
    out_x[(size_t)n*3+2] = coord[(size_t)n*3+2] + xv.z * inv;
}

extern "C" void kernel_launch(void* const* d_in, const int* in_sizes, int n_in,
                              void* d_out, int out_size, void* d_ws, size_t ws_size,
                              hipStream_t stream) {
    const float* node_feat = (const float*)d_in[0];
    const float* coord     = (const float*)d_in[1];
    const float* edge_feat = (const float*)d_in[2];
    const int*   src       = (const int*)d_in[3];
    const int*   dst       = (const int*)d_in[4];
    const float* We1 = (const float*)d_in[5];
    const float* be1 = (const float*)d_in[6];
    const float* We2 = (const float*)d_in[7];
    const float* be2 = (const float*)d_in[8];
    const float* Wn1 = (const float*)d_in[9];
    const float* bn1 = (const float*)d_in[10];
    const float* Wn2 = (const float*)d_in[11];
    const float* bn2 = (const float*)d_in[12];
    const float* Wc1 = (const float*)d_in[13];
    const float* bc1 = (const float*)d_in[14];
    const float* Wc2 = (const float*)d_in[15];

    int N = in_sizes[0] / TIN;
    int E = in_sizes[3];

    float* out_h = (float*)d_out;
    float* out_x = out_h + (size_t)N * TOUT;

    // workspace layout (16B-aligned blocks first)
    uint4*        efA     = (uint4*)d_ws;                        // N*MAXDEG (102 MB)
    float4*       coord4  = (float4*)(efA + ((size_t)N << 6));   // N
    float4*       xd4     = coord4 + N;                          // N
    float*        h_acc   = (float*)(xd4 + N);                   // N*32
    unsigned int* node_bf = (unsigned int*)(h_acc + (size_t)N * THID); // N*16
    int*          srcA    = (int*)(node_bf + (size_t)N * 16);    // N*MAXDEG
    int*          cnt     = srcA + ((size_t)N << 6);             // N+1
    size_t need = (size_t)((char*)(cnt + N + 1) - (char*)d_ws);

    if (need <= ws_size) {
        conv_node_kernel<<<2048, 256, 0, stream>>>(node_feat, node_bf, N * 16);
        conv_coord_kernel<<<(N + 255) / 256, 256, 0, stream>>>(coord, coord4, N);
        hipMemsetAsync(cnt, 0, (size_t)(N + 1) * 4, stream);
        record_rank_kernel<<<(E + 255) / 256, 256, 0, stream>>>(
            src, dst, edge_feat, cnt, srcA, efA, E);
        int nchunks = (N + CHUNK - 1) / CHUNK;
        egnn_fused<<<(nchunks + 3) / 4, 256, 0, stream>>>(
            (const uint4*)node_bf, coord4, srcA, efA, cnt,
            We1, be1, We2, be2, Wc1, bc1, Wc2,
            (float4*)h_acc, xd4, N);
        ovf_fix_node<<<(N + 255) / 256, 256, 0, stream>>>(
            node_feat, coord, edge_feat, src, dst, cnt,
            We1, be1, We2, be2, Wc1, bc1, Wc2, h_acc, xd4, N, E);
        egnn_node<<<(N + 255) / 256, 256, 0, stream>>>(
            node_feat, coord, Wn1, bn1, Wn2, bn2,
            h_acc, xd4, out_h, out_x, N);
    } else {
        float* fh_acc = (float*)d_ws;
        float* fx_acc = fh_acc + (size_t)N * THID;   // [N][4]
        hipMemsetAsync(d_ws, 0, sizeof(float) * (size_t)N * (THID + 4), stream);
        egnn_edge_atomic<<<(E + 255) / 256, 256, 0, stream>>>(
            node_feat, coord, edge_feat, src, dst,
            We1, be1, We2, be2, Wc1, bc1, Wc2,
            fh_acc, fx_acc, E);
        egnn_node<<<(N + 255) / 256, 256, 0, stream>>>(
            node_feat, coord, Wn1, bn1, Wn2, bn2,
            fh_acc, (const float4*)fx_acc, out_h, out_x, N);
    }
}

// Round 10
// 476.352 us; speedup vs baseline: 1.0917x; 1.0917x over previous
//
#include <hip/hip_runtime.h>
#include <math.h>

#define TIN   32
#define THID  32
#define TOUT  32
#define TEDGE 8
#define CHUNK 4        // nodes per wave in fused kernel
#define MAXDEG 64      // padded slots per node (P(Poisson(32)>64) ~ 1e-8)

typedef __attribute__((ext_vector_type(8))) short bf16x8;
typedef __attribute__((ext_vector_type(4))) float f32x4;

#define MFMA16(a, b, c) __builtin_amdgcn_mfma_f32_16x16x32_bf16((a), (b), (c), 0, 0, 0)

__device__ __forceinline__ unsigned int cvtpk(float lo, float hi) {
    unsigned int r;
    asm("v_cvt_pk_bf16_f32 %0, %1, %2" : "=v"(r) : "v"(lo), "v"(hi));
    return r;
}

__device__ __forceinline__ float silu_f(float x) {
    float e = __expf(-x);
    return x * __builtin_amdgcn_rcpf(1.0f + e);
}

__device__ __forceinline__ float bflo(unsigned int u) { return __uint_as_float(u << 16); }
__device__ __forceinline__ float bfhi(unsigned int u) { return __uint_as_float(u & 0xFFFF0000u); }

union U4F { unsigned int u[4]; bf16x8 v; };
union U4Q { uint4 q; bf16x8 v; };

__device__ __forceinline__ bf16x8 pack8bf(const float* f) {
    U4F t;
    t.u[0] = cvtpk(f[0], f[1]);
    t.u[1] = cvtpk(f[2], f[3]);
    t.u[2] = cvtpk(f[4], f[5]);
    t.u[3] = cvtpk(f[6], f[7]);
    return t.v;
}

__device__ __forceinline__ bf16x8 load_wT(const float* __restrict__ W, int kbase, int ch, int Kreal) {
    float f[8];
    #pragma unroll
    for (int e = 0; e < 8; ++e) {
        int k = kbase + e;
        f[e] = (k < Kreal) ? W[k * 32 + ch] : 0.0f;
    }
    return pack8bf(f);
}

// Layer-1 third K-block, record layout: g1 slots = rows 64..71 {radial, ef0..ef6};
// g0 slots = {row 72 (ef7), bias}; g2,g3 = 0.
__device__ __forceinline__ bf16x8 load_wA12(const float* __restrict__ We1,
                                            const float* __restrict__ be1, int g, int ch) {
    float f[8];
    #pragma unroll
    for (int e = 0; e < 8; ++e) f[e] = 0.0f;
    if (g == 0) { f[0] = We1[72 * 32 + ch]; f[1] = be1[ch]; }
    else if (g == 1) {
        #pragma unroll
        for (int e = 0; e < 8; ++e) f[e] = We1[(64 + e) * 32 + ch];
    }
    return pack8bf(f);
}

// ---------------- phase 0a: node_feat f32 -> bf16 rows ----------------
__global__ __launch_bounds__(256) void conv_node_kernel(
    const float* __restrict__ nf, unsigned int* __restrict__ nb, int total /* N*16 */)
{
    int i = blockIdx.x * 256 + threadIdx.x;
    int stride = gridDim.x * 256;
    for (; i < total; i += stride) {
        float2 v = reinterpret_cast<const float2*>(nf)[i];
        nb[i] = cvtpk(v.x, v.y);
    }
}

// ---------------- phase 0b: coord [N,3] -> padded float4 ----------------
__global__ __launch_bounds__(256) void conv_coord_kernel(
    const float* __restrict__ c, float4* __restrict__ c4, int N)
{
    int i = blockIdx.x * 256 + threadIdx.x;
    int stride = gridDim.x * 256;
    for (; i < N; i += stride) {
        float4 v;
        v.x = c[3*(size_t)i+0]; v.y = c[3*(size_t)i+1]; v.z = c[3*(size_t)i+2]; v.w = 0.0f;
        c4[i] = v;
    }
}

// ---------------- phase 1: merged rank + geometry + record (direct placement) ----------------
// rec[slot] = 2 x uint4 at slot = dst*MAXDEG + rank:
//  #0: {src, cvtpk(xd0,xd1), cvtpk(xd2,ef7), 0}
//  #1: {cvtpk(radial,ef0), cvtpk(ef1,ef2), cvtpk(ef3,ef4), cvtpk(ef5,ef6)}
__global__ __launch_bounds__(256) void record_rank_kernel(
    const int* __restrict__ src,
    const int* __restrict__ dst,
    const float4* __restrict__ coord4,
    const float* __restrict__ edge_feat,
    int* __restrict__ cnt,          // [N+1]
    uint4* __restrict__ recs,
    int E)
{
    int e = blockIdx.x * 256 + threadIdx.x;
    if (e >= E) return;
    int s = src[e], d = dst[e];
    int rank = atomicAdd(&cnt[d], 1);
    if (rank >= MAXDEG) return;     // overflow handled by ovf_fix_node (dead path)

    float4 cs = coord4[s];
    float4 cd = coord4[d];
    float dx0 = cs.x - cd.x, dx1 = cs.y - cd.y, dx2 = cs.z - cd.z;
    float radial = dx0*dx0 + dx1*dx1 + dx2*dx2;
    float invn = __builtin_amdgcn_rcpf(sqrtf(radial) + 1e-30f);
    dx0 *= invn; dx1 *= invn; dx2 *= invn;

    const float4* ep = reinterpret_cast<const float4*>(edge_feat + (size_t)e * TEDGE);
    float4 e0 = ep[0], e1 = ep[1];

    size_t slot = ((size_t)d << 6) + rank;   // MAXDEG == 64
    uint4 r0, r1;
    r0.x = (unsigned int)s;
    r0.y = cvtpk(dx0, dx1);
    r0.z = cvtpk(dx2, e1.w);     // low=xd2, high=ef7
    r0.w = 0u;
    r1.x = cvtpk(radial, e0.x);
    r1.y = cvtpk(e0.y, e0.z);
    r1.z = cvtpk(e0.w, e1.x);
    r1.w = cvtpk(e1.y, e1.z);
    recs[2*slot + 0] = r0;
    recs[2*slot + 1] = r1;
}

// ---------------- phase 2: FUSED edge MLP + segment aggregation ----------------
__global__ __launch_bounds__(256) void egnn_fused(
    const uint4* __restrict__ node_bf4,   // [N][4] uint4 (64B bf16 rows)
    const uint4* __restrict__ recs,       // [N*MAXDEG][2] uint4
    const int*  __restrict__ cnt,         // [N] true degrees
    const float* __restrict__ We1,
    const float* __restrict__ be1,
    const float* __restrict__ We2,
    const float* __restrict__ be2,
    const float* __restrict__ Wc1,
    const float* __restrict__ bc1,
    const float* __restrict__ Wc2,
    float4* __restrict__ h_acc4,          // [N][8] float4
    float4* __restrict__ xd4,             // [N] {x0,x1,x2,deg}
    int N)
{
    const int lane = threadIdx.x & 63;
    const int wid  = threadIdx.x >> 6;
    const int r    = lane & 15;
    const int g    = lane >> 4;

    bf16x8 A10[2], A11[2], A12[2], A2[2], A3[2];
    A10[0] = load_wT(We1,      8*g, r,      73);
    A10[1] = load_wT(We1,      8*g, 16 + r, 73);
    A11[0] = load_wT(We1, 32 + 8*g, r,      73);
    A11[1] = load_wT(We1, 32 + 8*g, 16 + r, 73);
    A12[0] = load_wA12(We1, be1, g, r);
    A12[1] = load_wA12(We1, be1, g, 16 + r);
    A2[0] = load_wT(We2, 8*g, r, 32);      A2[1] = load_wT(We2, 8*g, 16 + r, 32);
    A3[0] = load_wT(Wc1, 8*g, r, 32);      A3[1] = load_wT(Wc1, 8*g, 16 + r, 32);

    float be2v[8], bc1v[8], wc2v[8];
    #pragma unroll
    for (int h = 0; h < 2; ++h)
        #pragma unroll
        for (int q = 0; q < 4; ++q) {
            int ch = 16*h + 4*g + q;
            be2v[4*h+q] = be2[ch];
            bc1v[4*h+q] = bc1[ch];
            wc2v[4*h+q] = Wc2[ch];
        }

    const bool Hhi = ((g >> 1) & 1) != 0;
    const int  s0L = 32 * (g & 1) + r;
    const int  s1L = s0L + 16;

    int c0n = (blockIdx.x * 4 + wid) * CHUNK;

    for (int n = c0n; n < c0n + CHUNK && n < N; ++n) {
        int deg = cnt[n];
        int len = deg < MAXDEG ? deg : MAXDEG;
        size_t segbase = ((size_t)n << 6);

        U4Q Bd; Bd.q = node_bf4[(size_t)n * 4 + g];

        // per-node dst-term of layer 1 (constant across the segment)
        f32x4 z4 = {0.f,0.f,0.f,0.f};
        f32x4 dst0 = MFMA16(A11[0], Bd.v, z4);
        f32x4 dst1 = MFMA16(A11[1], Bd.v, z4);

        float ha0[4] = {0.f,0.f,0.f,0.f}, ha1[4] = {0.f,0.f,0.f,0.f};
        float xa0 = 0.f, xa1 = 0.f, xa2 = 0.f;

        for (int t = 0; t < len; t += 16) {
            int idx = t + r;
            bool valid = idx < len;
            size_t slot = segbase + (valid ? idx : 0);

            uint4 rc = recs[2*slot + (g & 1)];
            int srcv = __shfl((int)rc.x, r, 64);

            U4Q Bs; Bs.q = node_bf4[(size_t)srcv * 4 + g];

            U4F Bk2;
            Bk2.u[0] = 0u; Bk2.u[1] = 0u; Bk2.u[2] = 0u; Bk2.u[3] = 0u;
            if (g == 0) {
                Bk2.u[0] = (rc.z >> 16) | 0x3F800000u;   // {ef7, 1.0 bias}
            } else if (g == 1) {
                Bk2.u[0] = rc.x; Bk2.u[1] = rc.y; Bk2.u[2] = rc.z; Bk2.u[3] = rc.w;
            }

            // ---- layer 1 (dst term pre-accumulated, bias folded) ----
            f32x4 acc0 = dst0, acc1 = dst1;
            acc0 = MFMA16(A10[0], Bs.v,   acc0);
            acc0 = MFMA16(A12[0], Bk2.v,  acc0);
            acc1 = MFMA16(A10[1], Bs.v,   acc1);
            acc1 = MFMA16(A12[1], Bk2.v,  acc1);

            unsigned int pk0 = cvtpk(silu_f(acc0[0]), silu_f(acc0[1]));
            unsigned int pk1 = cvtpk(silu_f(acc0[2]), silu_f(acc0[3]));
            unsigned int pk2 = cvtpk(silu_f(acc1[0]), silu_f(acc1[1]));
            unsigned int pk3 = cvtpk(silu_f(acc1[2]), silu_f(acc1[3]));

            // ---- transpose a1 -> B2 ----
            unsigned int al0 = __shfl(pk0, s0L, 64), al1 = __shfl(pk1, s0L, 64);
            unsigned int ah0 = __shfl(pk2, s0L, 64), ah1 = __shfl(pk3, s0L, 64);
            unsigned int bl0 = __shfl(pk0, s1L, 64), bl1 = __shfl(pk1, s1L, 64);
            unsigned int bh0 = __shfl(pk2, s1L, 64), bh1 = __shfl(pk3, s1L, 64);
            U4F B2u;
            B2u.u[0] = Hhi ? ah0 : al0;  B2u.u[1] = Hhi ? ah1 : al1;
            B2u.u[2] = Hhi ? bh0 : bl0;  B2u.u[3] = Hhi ? bh1 : bl1;

            // ---- layer 2 ----
            f32x4 m0, m1;
            #pragma unroll
            for (int q = 0; q < 4; ++q) { m0[q] = be2v[q]; m1[q] = be2v[4+q]; }
            m0 = MFMA16(A2[0], B2u.v, m0);
            m1 = MFMA16(A2[1], B2u.v, m1);

            float vm = valid ? 1.0f : 0.0f;
            float s00 = silu_f(m0[0]) * vm, s01 = silu_f(m0[1]) * vm;
            float s02 = silu_f(m0[2]) * vm, s03 = silu_f(m0[3]) * vm;
            float s10 = silu_f(m1[0]) * vm, s11 = silu_f(m1[1]) * vm;
            float s12 = silu_f(m1[2]) * vm, s13 = silu_f(m1[3]) * vm;

            ha0[0] += s00; ha0[1] += s01; ha0[2] += s02; ha0[3] += s03;
            ha1[0] += s10; ha1[1] += s11; ha1[2] += s12; ha1[3] += s13;

            unsigned int mpk0 = cvtpk(s00, s01);
            unsigned int mpk1 = cvtpk(s02, s03);
            unsigned int mpk2 = cvtpk(s10, s11);
            unsigned int mpk3 = cvtpk(s12, s13);

            // ---- transpose msg -> B3 ----
            unsigned int cl0 = __shfl(mpk0, s0L, 64), cl1 = __shfl(mpk1, s0L, 64);
            unsigned int ch0 = __shfl(mpk2, s0L, 64), ch1 = __shfl(mpk3, s0L, 64);
            unsigned int dl0 = __shfl(mpk0, s1L, 64), dl1 = __shfl(mpk1, s1L, 64);
            unsigned int dh0 = __shfl(mpk2, s1L, 64), dh1 = __shfl(mpk3, s1L, 64);
            U4F B3u;
            B3u.u[0] = Hhi ? ch0 : cl0;  B3u.u[1] = Hhi ? ch1 : cl1;
            B3u.u[2] = Hhi ? dh0 : dl0;  B3u.u[3] = Hhi ? dh1 : dl1;

            // ---- layer 3: coord gate ----
            f32x4 c0, c1;
            #pragma unroll
            for (int q = 0; q < 4; ++q) { c0[q] = bc1v[q]; c1[q] = bc1v[4+q]; }
            c0 = MFMA16(A3[0], B3u.v, c0);
            c1 = MFMA16(A3[1], B3u.v, c1);

            float gp = 0.0f;
            #pragma unroll
            for (int q = 0; q < 4; ++q) {
                gp = fmaf(silu_f(c0[q]), wc2v[q],   gp);
                gp = fmaf(silu_f(c1[q]), wc2v[4+q], gp);
            }
            gp += __shfl_xor(gp, 16, 64);
            gp += __shfl_xor(gp, 32, 64);

            float xd0 = bflo(rc.y), xd1 = bfhi(rc.y), xd2 = bflo(rc.z);
            xa0 = fmaf(gp * vm, xd0, xa0);
            xa1 = fmaf(gp * vm, xd1, xa1);
            xa2 = fmaf(gp * vm, xd2, xa2);
        }

        #pragma unroll
        for (int off = 1; off < 16; off <<= 1) {
            #pragma unroll
            for (int q = 0; q < 4; ++q) {
                ha0[q] += __shfl_xor(ha0[q], off, 64);
                ha1[q] += __shfl_xor(ha1[q], off, 64);
            }
            xa0 += __shfl_xor(xa0, off, 64);
            xa1 += __shfl_xor(xa1, off, 64);
            xa2 += __shfl_xor(xa2, off, 64);
        }

        if (r == 0) {
            float4 v0; v0.x = ha0[0]; v0.y = ha0[1]; v0.z = ha0[2]; v0.w = ha0[3];
            float4 v1; v1.x = ha1[0]; v1.y = ha1[1]; v1.z = ha1[2]; v1.w = ha1[3];
            h_acc4[(size_t)n * 8 + g]     = v0;
            h_acc4[(size_t)n * 8 + 4 + g] = v1;
            if (g == 0) {
                float4 xv; xv.x = xa0; xv.y = xa1; xv.z = xa2; xv.w = (float)deg;
                xd4[n] = xv;
            }
        }
    }
}

// ---------------- overflow fix-up: per-node check + exact scalar recompute ----------------
__global__ __launch_bounds__(256) void ovf_fix_node(
    const float* __restrict__ node_feat,
    const float* __restrict__ coord,
    const float* __restrict__ edge_feat,
    const int* __restrict__ src,
    const int* __restrict__ dst,
    const int* __restrict__ cnt,
    const float* __restrict__ We1,
    const float* __restrict__ be1,
    const float* __restrict__ We2,
    const float* __restrict__ be2,
    const float* __restrict__ Wc1,
    const float* __restrict__ bc1,
    const float* __restrict__ Wc2,
    float* __restrict__ h_acc,
    float4* __restrict__ xd4,
    int N, int E)
{
    int n = blockIdx.x * 256 + threadIdx.x;
    if (n >= N) return;
    if (cnt[n] <= MAXDEG) return;

    float hsum[THID];
    #pragma unroll
    for (int j = 0; j < THID; ++j) hsum[j] = 0.f;
    float xs0 = 0.f, xs1 = 0.f, xs2 = 0.f;
    int degc = 0;
    for (int ee = 0; ee < E; ++ee) {
        if (dst[ee] != n) continue;
        ++degc;
        int ss = src[ee];
        float dx0 = coord[3*(size_t)ss+0] - coord[3*(size_t)n+0];
        float dx1 = coord[3*(size_t)ss+1] - coord[3*(size_t)n+1];
        float dx2 = coord[3*(size_t)ss+2] - coord[3*(size_t)n+2];
        float radial = dx0*dx0 + dx1*dx1 + dx2*dx2;
        float invn = 1.0f / (sqrtf(radial) + 1e-30f);
        dx0 *= invn; dx1 *= invn; dx2 *= invn;
        float f[73];
        for (int k = 0; k < 32; ++k) f[k] = node_feat[(size_t)ss*TIN + k];
        for (int k = 0; k < 32; ++k) f[32+k] = node_feat[(size_t)n*TIN + k];
        f[64] = radial;
        for (int k = 0; k < 8; ++k) f[65+k] = edge_feat[(size_t)ee*TEDGE + k];
        float a1[THID];
        for (int j = 0; j < THID; ++j) a1[j] = be1[j];
        for (int k = 0; k < 73; ++k) {
            float fk = f[k];
            for (int j = 0; j < THID; ++j) a1[j] = fmaf(fk, We1[k*THID + j], a1[j]);
        }
        for (int j = 0; j < THID; ++j) a1[j] = silu_f(a1[j]);
        float msg[THID];
        for (int j = 0; j < THID; ++j) msg[j] = be2[j];
        for (int k = 0; k < THID; ++k) {
            float fk = a1[k];
            for (int j = 0; j < THID; ++j) msg[j] = fmaf(fk, We2[k*THID + j], msg[j]);
        }
        for (int j = 0; j < THID; ++j) msg[j] = silu_f(msg[j]);
        float c1[THID];
        for (int j = 0; j < THID; ++j) c1[j] = bc1[j];
        for (int k = 0; k < THID; ++k) {
            float fk = msg[k];
            for (int j = 0; j < THID; ++j) c1[j] = fmaf(fk, Wc1[k*THID + j], c1[j]);
        }
        float gate = 0.0f;
        for (int j = 0; j < THID; ++j) gate = fmaf(silu_f(c1[j]), Wc2[j], gate);
        for (int j = 0; j < THID; ++j) hsum[j] += msg[j];
        xs0 += gate * dx0; xs1 += gate * dx1; xs2 += gate * dx2;
    }
    for (int j = 0; j < THID; ++j) h_acc[(size_t)n * THID + j] = hsum[j];
    float4 xv; xv.x = xs0; xv.y = xs1; xv.z = xs2; xv.w = (float)degc;
    xd4[n] = xv;
}

// ---------------- fallback: atomic edge kernel (small-ws path) ----------------
__global__ __launch_bounds__(256) void egnn_edge_atomic(
    const float* __restrict__ node_feat,
    const float* __restrict__ coord,
    const float* __restrict__ edge_feat,
    const int*   __restrict__ src,
    const int*   __restrict__ dst,
    const float* __restrict__ We1,
    const float* __restrict__ be1,
    const float* __restrict__ We2,
    const float* __restrict__ be2,
    const float* __restrict__ Wc1,
    const float* __restrict__ bc1,
    const float* __restrict__ Wc2,
    float* __restrict__ h_acc,
    float* __restrict__ x_acc,   // [N][4] {x,y,z,deg}
    int E)
{
    int e = blockIdx.x * 256 + threadIdx.x;
    if (e >= E) return;
    int s = src[e];
    int d = dst[e];
    float dx0 = coord[3*(size_t)s+0] - coord[3*(size_t)d+0];
    float dx1 = coord[3*(size_t)s+1] - coord[3*(size_t)d+1];
    float dx2 = coord[3*(size_t)s+2] - coord[3*(size_t)d+2];
    float radial = dx0*dx0 + dx1*dx1 + dx2*dx2;
    float invn = 1.0f / (sqrtf(radial) + 1e-30f);
    dx0 *= invn; dx1 *= invn; dx2 *= invn;
    float f[73];
    #pragma unroll
    for (int i = 0; i < 32; ++i) f[i] = node_feat[(size_t)s*TIN + i];
    #pragma unroll
    for (int i = 0; i < 32; ++i) f[32+i] = node_feat[(size_t)d*TIN + i];
    f[64] = radial;
    #pragma unroll
    for (int i = 0; i < 8; ++i) f[65+i] = edge_feat[(size_t)e*TEDGE + i];
    float a1[THID];
    #pragma unroll
    for (int j = 0; j < THID; ++j) a1[j] = be1[j];
    for (int k = 0; k < 73; ++k) {
        float fk = f[k];
        #pragma unroll
        for (int j = 0; j < THID; ++j) a1[j] = fmaf(fk, We1[k*THID + j], a1[j]);
    }
    #pragma unroll
    for (int j = 0; j < THID; ++j) a1[j] = silu_f(a1[j]);
    float msg[THID];
    #pragma unroll
    for (int j = 0; j < THID; ++j) msg[j] = be2[j];
    for (int k = 0; k < THID; ++k) {
        float fk = a1[k];
        #pragma unroll
        for (int j = 0; j < THID; ++j) msg[j] = fmaf(fk, We2[k*THID + j], msg[j]);
    }
    #pragma unroll
    for (int j = 0; j < THID; ++j) msg[j] = silu_f(msg[j]);
    float c1[THID];
    #pragma unroll
    for (int j = 0; j < THID; ++j) c1[j] = bc1[j];
    for (int k = 0; k < THID; ++k) {
        float fk = msg[k];
        #pragma unroll
        for (int j = 0; j < THID; ++j) c1[j] = fmaf(fk, Wc1[k*THID + j], c1[j]);
    }
    float gate = 0.0f;
    #pragma unroll
    for (int j = 0; j < THID; ++j) gate = fmaf(silu_f(c1[j]), Wc2[j], gate);
    float* ha = h_acc + (size_t)d * THID;
    #pragma unroll
    for (int j = 0; j < THID; ++j) atomicAdd(ha + j, msg[j]);
    atomicAdd(x_acc + (size_t)d*4 + 0, gate * dx0);
    atomicAdd(x_acc + (size_t)d*4 + 1, gate * dx1);
    atomicAdd(x_acc + (size_t)d*4 + 2, gate * dx2);
    atomicAdd(x_acc + (size_t)d*4 + 3, 1.0f);
}

// ---------------- phase 3: node update ----------------
__global__ __launch_bounds__(256) void egnn_node(
    const float* __restrict__ node_feat,
    const float* __restrict__ coord,
    const float* __restrict__ Wn1,
    const float* __restrict__ bn1,
    const float* __restrict__ Wn2,
    const float* __restrict__ bn2,
    const float* __restrict__ h_acc,
    const float4* __restrict__ xd4,   // {x,y,z,deg}
    float* __restrict__ out_h,
    float* __restrict__ out_x,
    int N)
{
    int n = blockIdx.x * 256 + threadIdx.x;
    if (n >= N) return;

    float f2[2*TIN];
    {
        const float4* p = reinterpret_cast<const float4*>(node_feat + (size_t)n * TIN);
        #pragma unroll
        for (int i = 0; i < TIN/4; ++i) {
            float4 v = p[i];
            f2[4*i+0]=v.x; f2[4*i+1]=v.y; f2[4*i+2]=v.z; f2[4*i+3]=v.w;
        }
    }
    {
        const float4* p = reinterpret_cast<const float4*>(h_acc + (size_t)n * THID);
        #pragma unroll
        for (int i = 0; i < THID/4; ++i) {
            float4 v = p[i];
            f2[TIN+4*i+0]=v.x; f2[TIN+4*i+1]=v.y; f2[TIN+4*i+2]=v.z; f2[TIN+4*i+3]=v.w;
        }
    }

    float a[THID];
    #pragma unroll
    for (int j = 0; j < THID; ++j) a[j] = bn1[j];
    #pragma unroll
    for (int k = 0; k < 2*TIN; ++k) {
        float fk = f2[k];
        #pragma unroll
        for (int j = 0; j < THID; ++j) a[j] = fmaf(fk, Wn1[k*THID + j], a[j]);
    }
    #pragma unroll
    for (int j = 0; j < THID; ++j) a[j] = silu_f(a[j]);

    float h[TOUT];
    #pragma unroll
    for (int j = 0; j < TOUT; ++j) h[j] = bn2[j];
    #pragma unroll
    for (int k = 0; k < THID; ++k) {
        float fk = a[k];
        #pragma unroll
        for (int j = 0; j < TOUT; ++j) h[j] = fmaf(fk, Wn2[k*TOUT + j], h[j]);
    }

    float4* po = reinterpret_cast<float4*>(out_h + (size_t)n * TOUT);
    #pragma unroll
    for (int i = 0; i < TOUT/4; ++i) {
        float4 v; v.x=h[4*i+0]; v.y=h[4*i+1]; v.z=h[4*i+2]; v.w=h[4*i+3];
        po[i] = v;
    }

    float4 xv = xd4[n];
    float dg = fmaxf(xv.w, 1.0f);
    float inv = __builtin_amdgcn_rcpf(dg);
    out_x[(size_t)n*3+0] = coord[(size_t)n*3+0] + xv.x * inv;
    out_x[(size_t)n*3+1] = coord[(size_t)n*3+1] + xv.y * inv;
    out_x[(size_t)n*3+2] = coord[(size_t)n*3+2] + xv.z * inv;
}

extern "C" void kernel_launch(void* const* d_in, const int* in_sizes, int n_in,
                              void* d_out, int out_size, void* d_ws, size_t ws_size,
                              hipStream_t stream) {
    const float* node_feat = (const float*)d_in[0];
    const float* coord     = (const float*)d_in[1];
    const float* edge_feat = (const float*)d_in[2];
    const int*   src       = (const int*)d_in[3];
    const int*   dst       = (const int*)d_in[4];
    const float* We1 = (const float*)d_in[5];
    const float* be1 = (const float*)d_in[6];
    const float* We2 = (const float*)d_in[7];
    const float* be2 = (const float*)d_in[8];
    const float* Wn1 = (const float*)d_in[9];
    const float* bn1 = (const float*)d_in[10];
    const float* Wn2 = (const float*)d_in[11];
    const float* bn2 = (const float*)d_in[12];
    const float* Wc1 = (const float*)d_in[13];
    const float* bc1 = (const float*)d_in[14];
    const float* Wc2 = (const float*)d_in[15];

    int N = in_sizes[0] / TIN;
    int E = in_sizes[3];

    float* out_h = (float*)d_out;
    float* out_x = out_h + (size_t)N * TOUT;

    // workspace layout
    uint4*        recs    = (uint4*)d_ws;                              // N*MAXDEG*2 uint4 (32B/slot)
    unsigned int* node_bf = (unsigned int*)(recs + ((size_t)N << 6) * 2);
    float4*       coord4  = (float4*)(node_bf + (size_t)N * 16);
    float*        h_acc   = (float*)(coord4 + N);                      // N*32 f32
    float4*       xd4     = (float4*)(h_acc + (size_t)N * THID);       // N
    int*          cnt     = (int*)(xd4 + N);                           // N+1
    size_t need = (size_t)((char*)(cnt + N + 1) - (char*)d_ws);

    if (need <= ws_size) {
        conv_node_kernel<<<2048, 256, 0, stream>>>(node_feat, node_bf, N * 16);
        conv_coord_kernel<<<(N + 255) / 256, 256, 0, stream>>>(coord, coord4, N);
        hipMemsetAsync(cnt, 0, (size_t)(N + 1) * 4, stream);
        record_rank_kernel<<<(E + 255) / 256, 256, 0, stream>>>(
            src, dst, coord4, edge_feat, cnt, recs, E);
        int nchunks = (N + CHUNK - 1) / CHUNK;
        egnn_fused<<<(nchunks + 3) / 4, 256, 0, stream>>>(
            (const uint4*)node_bf, recs, cnt,
            We1, be1, We2, be2, Wc1, bc1, Wc2,
            (float4*)h_acc, xd4, N);
        ovf_fix_node<<<(N + 255) / 256, 256, 0, stream>>>(
            node_feat, coord, edge_feat, src, dst, cnt,
            We1, be1, We2, be2, Wc1, bc1, Wc2, h_acc, xd4, N, E);
        egnn_node<<<(N + 255) / 256, 256, 0, stream>>>(
            node_feat, coord, Wn1, bn1, Wn2, bn2,
            h_acc, xd4, out_h, out_x, N);
    } else {
        float* fh_acc = (float*)d_ws;
        float* fx_acc = fh_acc + (size_t)N * THID;   // [N][4]
        hipMemsetAsync(d_ws, 0, sizeof(float) * (size_t)N * (THID + 4), stream);
        egnn_edge_atomic<<<(E + 255) / 256, 256, 0, stream>>>(
            node_feat, coord, edge_feat, src, dst,
            We1, be1, We2, be2, Wc1, bc1, Wc2,
            fh_acc, fx_acc, E);
        egnn_node<<<(N + 255) / 256, 256, 0, stream>>>(
            node_feat, coord, Wn1, bn1, Wn2, bn2,
            fh_acc, (const float4*)fx_acc, out_h, out_x, N);
    }
}

// Round 11
// 463.171 us; speedup vs baseline: 1.1227x; 1.0285x over previous
//
#include <hip/hip_runtime.h>
#include <math.h>

#define TIN   32
#define THID  32
#define TOUT  32
#define TEDGE 8
#define CHUNK 4        // nodes per wave in fused kernel
#define MAXDEG 64      // padded slots per node (P(Poisson(32)>64) ~ 1e-8)

typedef __attribute__((ext_vector_type(8))) short bf16x8;
typedef __attribute__((ext_vector_type(4))) float f32x4;

#define MFMA16(a, b, c) __builtin_amdgcn_mfma_f32_16x16x32_bf16((a), (b), (c), 0, 0, 0)

__device__ __forceinline__ unsigned int cvtpk(float lo, float hi) {
    unsigned int r;
    asm("v_cvt_pk_bf16_f32 %0, %1, %2" : "=v"(r) : "v"(lo), "v"(hi));
    return r;
}

__device__ __forceinline__ float silu_f(float x) {
    float e = __expf(-x);
    return x * __builtin_amdgcn_rcpf(1.0f + e);
}

__device__ __forceinline__ float bflo(unsigned int u) { return __uint_as_float(u << 16); }
__device__ __forceinline__ float bfhi(unsigned int u) { return __uint_as_float(u & 0xFFFF0000u); }

union U4F { unsigned int u[4]; bf16x8 v; };
union U4Q { uint4 q; bf16x8 v; };

__device__ __forceinline__ bf16x8 pack8bf(const float* f) {
    U4F t;
    t.u[0] = cvtpk(f[0], f[1]);
    t.u[1] = cvtpk(f[2], f[3]);
    t.u[2] = cvtpk(f[4], f[5]);
    t.u[3] = cvtpk(f[6], f[7]);
    return t.v;
}

__device__ __forceinline__ bf16x8 load_wT(const float* __restrict__ W, int kbase, int ch, int Kreal) {
    float f[8];
    #pragma unroll
    for (int e = 0; e < 8; ++e) {
        int k = kbase + e;
        f[e] = (k < Kreal) ? W[k * 32 + ch] : 0.0f;
    }
    return pack8bf(f);
}

// Layer-1 third K-block, record layout: g1 slots = rows 64..71 {radial, ef0..ef6};
// g0 slots = {row 72 (ef7), bias}; g2,g3 = 0.
__device__ __forceinline__ bf16x8 load_wA12(const float* __restrict__ We1,
                                            const float* __restrict__ be1, int g, int ch) {
    float f[8];
    #pragma unroll
    for (int e = 0; e < 8; ++e) f[e] = 0.0f;
    if (g == 0) { f[0] = We1[72 * 32 + ch]; f[1] = be1[ch]; }
    else if (g == 1) {
        #pragma unroll
        for (int e = 0; e < 8; ++e) f[e] = We1[(64 + e) * 32 + ch];
    }
    return pack8bf(f);
}

// ---------------- phase 0: merged prep (node bf16 rows, coord4, cnt zero) ----------------
__global__ __launch_bounds__(256) void prep_kernel(
    const float* __restrict__ nf, const float* __restrict__ c,
    unsigned int* __restrict__ nb, float4* __restrict__ c4,
    int* __restrict__ cnt, int N)
{
    int i = blockIdx.x * 256 + threadIdx.x;
    int stride = gridDim.x * 256;
    int total = N * 16;
    for (int j = i; j < total; j += stride) {
        float2 v = reinterpret_cast<const float2*>(nf)[j];
        nb[j] = cvtpk(v.x, v.y);
    }
    for (int j = i; j < N; j += stride) {
        float4 v;
        v.x = c[3*(size_t)j+0]; v.y = c[3*(size_t)j+1]; v.z = c[3*(size_t)j+2]; v.w = 0.0f;
        c4[j] = v;
    }
    for (int j = i; j <= N; j += stride) cnt[j] = 0;
}

// ---------------- phase 1: merged rank + geometry + record (direct placement) ----------------
// rec[slot] = 2 x uint4 at slot = dst*MAXDEG + rank:
//  #0: {src, cvtpk(xd0,xd1), cvtpk(xd2,ef7), 0}
//  #1: {cvtpk(radial,ef0), cvtpk(ef1,ef2), cvtpk(ef3,ef4), cvtpk(ef5,ef6)}
__global__ __launch_bounds__(256) void record_rank_kernel(
    const int* __restrict__ src,
    const int* __restrict__ dst,
    const float4* __restrict__ coord4,
    const float* __restrict__ edge_feat,
    int* __restrict__ cnt,          // [N+1]
    uint4* __restrict__ recs,
    int E)
{
    int e = blockIdx.x * 256 + threadIdx.x;
    if (e >= E) return;
    int s = src[e], d = dst[e];
    int rank = atomicAdd(&cnt[d], 1);
    if (rank >= MAXDEG) return;     // overflow handled by ovf_fix_node (dead path)

    float4 cs = coord4[s];
    float4 cd = coord4[d];
    float dx0 = cs.x - cd.x, dx1 = cs.y - cd.y, dx2 = cs.z - cd.z;
    float radial = dx0*dx0 + dx1*dx1 + dx2*dx2;
    float invn = __builtin_amdgcn_rcpf(sqrtf(radial) + 1e-30f);
    dx0 *= invn; dx1 *= invn; dx2 *= invn;

    const float4* ep = reinterpret_cast<const float4*>(edge_feat + (size_t)e * TEDGE);
    float4 e0 = ep[0], e1 = ep[1];

    size_t slot = ((size_t)d << 6) + rank;   // MAXDEG == 64
    uint4 r0, r1;
    r0.x = (unsigned int)s;
    r0.y = cvtpk(dx0, dx1);
    r0.z = cvtpk(dx2, e1.w);     // low=xd2, high=ef7
    r0.w = 0u;
    r1.x = cvtpk(radial, e0.x);
    r1.y = cvtpk(e0.y, e0.z);
    r1.z = cvtpk(e0.w, e1.x);
    r1.w = cvtpk(e1.y, e1.z);
    recs[2*slot + 0] = r0;
    recs[2*slot + 1] = r1;
}

// ---------------- phase 2: FUSED edge MLP + segment aggregation (prefetch pipelined) ----------------
__global__ __launch_bounds__(256) void egnn_fused(
    const uint4* __restrict__ node_bf4,   // [N][4] uint4 (64B bf16 rows)
    const uint4* __restrict__ recs,       // [N*MAXDEG][2] uint4
    const int*  __restrict__ cnt,         // [N] true degrees
    const float* __restrict__ We1,
    const float* __restrict__ be1,
    const float* __restrict__ We2,
    const float* __restrict__ be2,
    const float* __restrict__ Wc1,
    const float* __restrict__ bc1,
    const float* __restrict__ Wc2,
    float4* __restrict__ h_acc4,          // [N][8] float4
    float4* __restrict__ xd4,             // [N] {x0,x1,x2,deg}
    int N)
{
    const int lane = threadIdx.x & 63;
    const int wid  = threadIdx.x >> 6;
    const int r    = lane & 15;
    const int g    = lane >> 4;

    bf16x8 A10[2], A11[2], A12[2], A2[2], A3[2];
    A10[0] = load_wT(We1,      8*g, r,      73);
    A10[1] = load_wT(We1,      8*g, 16 + r, 73);
    A11[0] = load_wT(We1, 32 + 8*g, r,      73);
    A11[1] = load_wT(We1, 32 + 8*g, 16 + r, 73);
    A12[0] = load_wA12(We1, be1, g, r);
    A12[1] = load_wA12(We1, be1, g, 16 + r);
    A2[0] = load_wT(We2, 8*g, r, 32);      A2[1] = load_wT(We2, 8*g, 16 + r, 32);
    A3[0] = load_wT(Wc1, 8*g, r, 32);      A3[1] = load_wT(Wc1, 8*g, 16 + r, 32);

    float be2v[8], bc1v[8], wc2v[8];
    #pragma unroll
    for (int h = 0; h < 2; ++h)
        #pragma unroll
        for (int q = 0; q < 4; ++q) {
            int ch = 16*h + 4*g + q;
            be2v[4*h+q] = be2[ch];
            bc1v[4*h+q] = bc1[ch];
            wc2v[4*h+q] = Wc2[ch];
        }

    const bool Hhi = ((g >> 1) & 1) != 0;
    const int  s0L = 32 * (g & 1) + r;
    const int  s1L = s0L + 16;

    int c0n = (blockIdx.x * 4 + wid) * CHUNK;

    for (int n = c0n; n < c0n + CHUNK && n < N; ++n) {
        int deg = cnt[n];
        int len = deg < MAXDEG ? deg : MAXDEG;
        size_t segbase = ((size_t)n << 6);

        U4Q Bd; Bd.q = node_bf4[(size_t)n * 4 + g];

        // per-node dst-term of layer 1 (constant across the segment)
        f32x4 z4 = {0.f,0.f,0.f,0.f};
        f32x4 dst0 = MFMA16(A11[0], Bd.v, z4);
        f32x4 dst1 = MFMA16(A11[1], Bd.v, z4);

        float ha0[4] = {0.f,0.f,0.f,0.f}, ha1[4] = {0.f,0.f,0.f,0.f};
        float xa0 = 0.f, xa1 = 0.f, xa2 = 0.f;

        // ---- pipeline prologue: prefetch tile 0 ----
        uint4 rc_cur; rc_cur.x = 0u; rc_cur.y = 0u; rc_cur.z = 0u; rc_cur.w = 0u;
        U4Q Bs_cur; Bs_cur.q.x = 0u; Bs_cur.q.y = 0u; Bs_cur.q.z = 0u; Bs_cur.q.w = 0u;
        if (len > 0) {
            size_t slot0 = segbase + ((r < len) ? r : 0);
            rc_cur = recs[2*slot0 + (g & 1)];
            int srcv0 = __shfl((int)rc_cur.x, r, 64);
            Bs_cur.q = node_bf4[(size_t)srcv0 * 4 + g];
        }

        for (int t = 0; t < len; t += 16) {
            int idx = t + r;
            bool valid = idx < len;
            uint4 rc = rc_cur;
            U4Q Bs = Bs_cur;

            // ---- prefetch tile t+16 (issued before the compute chain) ----
            if (t + 16 < len) {
                int idx2 = t + 16 + r;
                size_t slot2 = segbase + ((idx2 < len) ? (size_t)idx2 : 0);
                rc_cur = recs[2*slot2 + (g & 1)];
                int srcv2 = __shfl((int)rc_cur.x, r, 64);
                Bs_cur.q = node_bf4[(size_t)srcv2 * 4 + g];
            }

            U4F Bk2;
            Bk2.u[0] = 0u; Bk2.u[1] = 0u; Bk2.u[2] = 0u; Bk2.u[3] = 0u;
            if (g == 0) {
                Bk2.u[0] = (rc.z >> 16) | 0x3F800000u;   // {ef7, 1.0 bias}
            } else if (g == 1) {
                Bk2.u[0] = rc.x; Bk2.u[1] = rc.y; Bk2.u[2] = rc.z; Bk2.u[3] = rc.w;
            }

            // ---- layer 1 (dst term pre-accumulated, bias folded) ----
            f32x4 acc0 = dst0, acc1 = dst1;
            acc0 = MFMA16(A10[0], Bs.v,   acc0);
            acc0 = MFMA16(A12[0], Bk2.v,  acc0);
            acc1 = MFMA16(A10[1], Bs.v,   acc1);
            acc1 = MFMA16(A12[1], Bk2.v,  acc1);

            unsigned int pk0 = cvtpk(silu_f(acc0[0]), silu_f(acc0[1]));
            unsigned int pk1 = cvtpk(silu_f(acc0[2]), silu_f(acc0[3]));
            unsigned int pk2 = cvtpk(silu_f(acc1[0]), silu_f(acc1[1]));
            unsigned int pk3 = cvtpk(silu_f(acc1[2]), silu_f(acc1[3]));

            // ---- transpose a1 -> B2 ----
            unsigned int al0 = __shfl(pk0, s0L, 64), al1 = __shfl(pk1, s0L, 64);
            unsigned int ah0 = __shfl(pk2, s0L, 64), ah1 = __shfl(pk3, s0L, 64);
            unsigned int bl0 = __shfl(pk0, s1L, 64), bl1 = __shfl(pk1, s1L, 64);
            unsigned int bh0 = __shfl(pk2, s1L, 64), bh1 = __shfl(pk3, s1L, 64);
            U4F B2u;
            B2u.u[0] = Hhi ? ah0 : al0;  B2u.u[1] = Hhi ? ah1 : al1;
            B2u.u[2] = Hhi ? bh0 : bl0;  B2u.u[3] = Hhi ? bh1 : bl1;

            // ---- layer 2 ----
            f32x4 m0, m1;
            #pragma unroll
            for (int q = 0; q < 4; ++q) { m0[q] = be2v[q]; m1[q] = be2v[4+q]; }
            m0 = MFMA16(A2[0], B2u.v, m0);
            m1 = MFMA16(A2[1], B2u.v, m1);

            float vm = valid ? 1.0f : 0.0f;
            float s00 = silu_f(m0[0]) * vm, s01 = silu_f(m0[1]) * vm;
            float s02 = silu_f(m0[2]) * vm, s03 = silu_f(m0[3]) * vm;
            float s10 = silu_f(m1[0]) * vm, s11 = silu_f(m1[1]) * vm;
            float s12 = silu_f(m1[2]) * vm, s13 = silu_f(m1[3]) * vm;

            ha0[0] += s00; ha0[1] += s01; ha0[2] += s02; ha0[3] += s03;
            ha1[0] += s10; ha1[1] += s11; ha1[2] += s12; ha1[3] += s13;

            unsigned int mpk0 = cvtpk(s00, s01);
            unsigned int mpk1 = cvtpk(s02, s03);
            unsigned int mpk2 = cvtpk(s10, s11);
            unsigned int mpk3 = cvtpk(s12, s13);

            // ---- transpose msg -> B3 ----
            unsigned int cl0 = __shfl(mpk0, s0L, 64), cl1 = __shfl(mpk1, s0L, 64);
            unsigned int ch0 = __shfl(mpk2, s0L, 64), ch1 = __shfl(mpk3, s0L, 64);
            unsigned int dl0 = __shfl(mpk0, s1L, 64), dl1 = __shfl(mpk1, s1L, 64);
            unsigned int dh0 = __shfl(mpk2, s1L, 64), dh1 = __shfl(mpk3, s1L, 64);
            U4F B3u;
            B3u.u[0] = Hhi ? ch0 : cl0;  B3u.u[1] = Hhi ? ch1 : cl1;
            B3u.u[2] = Hhi ? dh0 : dl0;  B3u.u[3] = Hhi ? dh1 : dl1;

            // ---- layer 3: coord gate ----
            f32x4 c0, c1;
            #pragma unroll
            for (int q = 0; q < 4; ++q) { c0[q] = bc1v[q]; c1[q] = bc1v[4+q]; }
            c0 = MFMA16(A3[0], B3u.v, c0);
            c1 = MFMA16(A3[1], B3u.v, c1);

            float gp = 0.0f;
            #pragma unroll
            for (int q = 0; q < 4; ++q) {
                gp = fmaf(silu_f(c0[q]), wc2v[q],   gp);
                gp = fmaf(silu_f(c1[q]), wc2v[4+q], gp);
            }
            gp += __shfl_xor(gp, 16, 64);
            gp += __shfl_xor(gp, 32, 64);

            float xd0 = bflo(rc.y), xd1 = bfhi(rc.y), xd2 = bflo(rc.z);
            xa0 = fmaf(gp * vm, xd0, xa0);
            xa1 = fmaf(gp * vm, xd1, xa1);
            xa2 = fmaf(gp * vm, xd2, xa2);
        }

        #pragma unroll
        for (int off = 1; off < 16; off <<= 1) {
            #pragma unroll
            for (int q = 0; q < 4; ++q) {
                ha0[q] += __shfl_xor(ha0[q], off, 64);
                ha1[q] += __shfl_xor(ha1[q], off, 64);
            }
            xa0 += __shfl_xor(xa0, off, 64);
            xa1 += __shfl_xor(xa1, off, 64);
            xa2 += __shfl_xor(xa2, off, 64);
        }

        if (r == 0) {
            float4 v0; v0.x = ha0[0]; v0.y = ha0[1]; v0.z = ha0[2]; v0.w = ha0[3];
            float4 v1; v1.x = ha1[0]; v1.y = ha1[1]; v1.z = ha1[2]; v1.w = ha1[3];
            h_acc4[(size_t)n * 8 + g]     = v0;
            h_acc4[(size_t)n * 8 + 4 + g] = v1;
            if (g == 0) {
                float4 xv; xv.x = xa0; xv.y = xa1; xv.z = xa2; xv.w = (float)deg;
                xd4[n] = xv;
            }
        }
    }
}

// ---------------- overflow fix-up: per-node check + exact scalar recompute ----------------
__global__ __launch_bounds__(256) void ovf_fix_node(
    const float* __restrict__ node_feat,
    const float* __restrict__ coord,
    const float* __restrict__ edge_feat,
    const int* __restrict__ src,
    const int* __restrict__ dst,
    const int* __restrict__ cnt,
    const float* __restrict__ We1,
    const float* __restrict__ be1,
    const float* __restrict__ We2,
    const float* __restrict__ be2,
    const float* __restrict__ Wc1,
    const float* __restrict__ bc1,
    const float* __restrict__ Wc2,
    float* __restrict__ h_acc,
    float4* __restrict__ xd4,
    int N, int E)
{
    int n = blockIdx.x * 256 + threadIdx.x;
    if (n >= N) return;
    if (cnt[n] <= MAXDEG) return;

    float hsum[THID];
    #pragma unroll
    for (int j = 0; j < THID; ++j) hsum[j] = 0.f;
    float xs0 = 0.f, xs1 = 0.f, xs2 = 0.f;
    int degc = 0;
    for (int ee = 0; ee < E; ++ee) {
        if (dst[ee] != n) continue;
        ++degc;
        int ss = src[ee];
        float dx0 = coord[3*(size_t)ss+0] - coord[3*(size_t)n+0];
        float dx1 = coord[3*(size_t)ss+1] - coord[3*(size_t)n+1];
        float dx2 = coord[3*(size_t)ss+2] - coord[3*(size_t)n+2];
        float radial = dx0*dx0 + dx1*dx1 + dx2*dx2;
        float invn = 1.0f / (sqrtf(radial) + 1e-30f);
        dx0 *= invn; dx1 *= invn; dx2 *= invn;
        float f[73];
        for (int k = 0; k < 32; ++k) f[k] = node_feat[(size_t)ss*TIN + k];
        for (int k = 0; k < 32; ++k) f[32+k] = node_feat[(size_t)n*TIN + k];
        f[64] = radial;
        for (int k = 0; k < 8; ++k) f[65+k] = edge_feat[(size_t)ee*TEDGE + k];
        float a1[THID];
        for (int j = 0; j < THID; ++j) a1[j] = be1[j];
        for (int k = 0; k < 73; ++k) {
            float fk = f[k];
            for (int j = 0; j < THID; ++j) a1[j] = fmaf(fk, We1[k*THID + j], a1[j]);
        }
        for (int j = 0; j < THID; ++j) a1[j] = silu_f(a1[j]);
        float msg[THID];
        for (int j = 0; j < THID; ++j) msg[j] = be2[j];
        for (int k = 0; k < THID; ++k) {
            float fk = a1[k];
            for (int j = 0; j < THID; ++j) msg[j] = fmaf(fk, We2[k*THID + j], msg[j]);
        }
        for (int j = 0; j < THID; ++j) msg[j] = silu_f(msg[j]);
        float c1[THID];
        for (int j = 0; j < THID; ++j) c1[j] = bc1[j];
        for (int k = 0; k < THID; ++k) {
            float fk = msg[k];
            for (int j = 0; j < THID; ++j) c1[j] = fmaf(fk, Wc1[k*THID + j], c1[j]);
        }
        float gate = 0.0f;
        for (int j = 0; j < THID; ++j) gate = fmaf(silu_f(c1[j]), Wc2[j], gate);
        for (int j = 0; j < THID; ++j) hsum[j] += msg[j];
        xs0 += gate * dx0; xs1 += gate * dx1; xs2 += gate * dx2;
    }
    for (int j = 0; j < THID; ++j) h_acc[(size_t)n * THID + j] = hsum[j];
    float4 xv; xv.x = xs0; xv.y = xs1; xv.z = xs2; xv.w = (float)degc;
    xd4[n] = xv;
}

// ---------------- fallback: atomic edge kernel (small-ws path) ----------------
__global__ __launch_bounds__(256) void egnn_edge_atomic(
    const float* __restrict__ node_feat,
    const float* __restrict__ coord,
    const float* __restrict__ edge_feat,
    const int*   __restrict__ src,
    const int*   __restrict__ dst,
    const float* __restrict__ We1,
    const float* __restrict__ be1,
    const float* __restrict__ We2,
    const float* __restrict__ be2,
    const float* __restrict__ Wc1,
    const float* __restrict__ bc1,
    const float* __restrict__ Wc2,
    float* __restrict__ h_acc,
    float* __restrict__ x_acc,   // [N][4] {x,y,z,deg}
    int E)
{
    int e = blockIdx.x * 256 + threadIdx.x;
    if (e >= E) return;
    int s = src[e];
    int d = dst[e];
    float dx0 = coord[3*(size_t)s+0] - coord[3*(size_t)d+0];
    float dx1 = coord[3*(size_t)s+1] - coord[3*(size_t)d+1];
    float dx2 = coord[3*(size_t)s+2] - coord[3*(size_t)d+2];
    float radial = dx0*dx0 + dx1*dx1 + dx2*dx2;
    float invn = 1.0f / (sqrtf(radial) + 1e-30f);
    dx0 *= invn; dx1 *= invn; dx2 *= invn;
    float f[73];
    #pragma unroll
    for (int i = 0; i < 32; ++i) f[i] = node_feat[(size_t)s*TIN + i];
    #pragma unroll
    for (int i = 0; i < 32; ++i) f[32+i] = node_feat[(size_t)d*TIN + i];
    f[64] = radial;
    #pragma unroll
    for (int i = 0; i < 8; ++i) f[65+i] = edge_feat[(size_t)e*TEDGE + i];
    float a1[THID];
    #pragma unroll
    for (int j = 0; j < THID; ++j) a1[j] = be1[j];
    for (int k = 0; k < 73; ++k) {
        float fk = f[k];
        #pragma unroll
        for (int j = 0; j < THID; ++j) a1[j] = fmaf(fk, We1[k*THID + j], a1[j]);
    }
    #pragma unroll
    for (int j = 0; j < THID; ++j) a1[j] = silu_f(a1[j]);
    float msg[THID];
    #pragma unroll
    for (int j = 0; j < THID; ++j) msg[j] = be2[j];
    for (int k = 0; k < THID; ++k) {
        float fk = a1[k];
        #pragma unroll
        for (int j = 0; j < THID; ++j) msg[j] = fmaf(fk, We2[k*THID + j], msg[j]);
    }
    #pragma unroll
    for (int j = 0; j < THID; ++j) msg[j] = silu_f(msg[j]);
    float c1[THID];
    #pragma unroll
    for (int j = 0; j < THID; ++j) c1[j] = bc1[j];
    for (int k = 0; k < THID; ++k) {
        float fk = msg[k];
        #pragma unroll
        for (int j = 0; j < THID; ++j) c1[j] = fmaf(fk, Wc1[k*THID + j], c1[j]);
    }
    float gate = 0.0f;
    #pragma unroll
    for (int j = 0; j < THID; ++j) gate = fmaf(silu_f(c1[j]), Wc2[j], gate);
    float* ha = h_acc + (size_t)d * THID;
    #pragma unroll
    for (int j = 0; j < THID; ++j) atomicAdd(ha + j, msg[j]);
    atomicAdd(x_acc + (size_t)d*4 + 0, gate * dx0);
    atomicAdd(x_acc + (size_t)d*4 + 1, gate * dx1);
    atomicAdd(x_acc + (size_t)d*4 + 2, gate * dx2);
    atomicAdd(x_acc + (size_t)d*4 + 3, 1.0f);
}

// ---------------- phase 3: node update ----------------
__global__ __launch_bounds__(256) void egnn_node(
    const float* __restrict__ node_feat,
    const float* __restrict__ coord,
    const float* __restrict__ Wn1,
    const float* __restrict__ bn1,
    const float* __restrict__ Wn2,
    const float* __restrict__ bn2,
    const float* __restrict__ h_acc,
    const float4* __restrict__ xd4,   // {x,y,z,deg}
    float* __restrict__ out_h,
    float* __restrict__ out_x,
    int N)
{
    int n = blockIdx.x * 256 + threadIdx.x;
    if (n >= N) return;

    float f2[2*TIN];
    {
        const float4* p = reinterpret_cast<const float4*>(node_feat + (size_t)n * TIN);
        #pragma unroll
        for (int i = 0; i < TIN/4; ++i) {
            float4 v = p[i];
            f2[4*i+0]=v.x; f2[4*i+1]=v.y; f2[4*i+2]=v.z; f2[4*i+3]=v.w;
        }
    }
    {
        const float4* p = reinterpret_cast<const float4*>(h_acc + (size_t)n * THID);
        #pragma unroll
        for (int i = 0; i < THID/4; ++i) {
            float4 v = p[i];
            f2[TIN+4*i+0]=v.x; f2[TIN+4*i+1]=v.y; f2[TIN+4*i+2]=v.z; f2[TIN+4*i+3]=v.w;
        }
    }

    float a[THID];
    #pragma unroll
    for (int j = 0; j < THID; ++j) a[j] = bn1[j];
    #pragma unroll
    for (int k = 0; k < 2*TIN; ++k) {
        float fk = f2[k];
        #pragma unroll
        for (int j = 0; j < THID; ++j) a[j] = fmaf(fk, Wn1[k*THID + j], a[j]);
    }
    #pragma unroll
    for (int j = 0; j < THID; ++j) a[j] = silu_f(a[j]);

    float h[TOUT];
    #pragma unroll
    for (int j = 0; j < TOUT; ++j) h[j] = bn2[j];
    #pragma unroll
    for (int k = 0; k < THID; ++k) {
        float fk = a[k];
        #pragma unroll
        for (int j = 0; j < TOUT; ++j) h[j] = fmaf(fk, Wn2[k*TOUT + j], h[j]);
    }

    float4* po = reinterpret_cast<float4*>(out_h + (size_t)n * TOUT);
    #pragma unroll
    for (int i = 0; i < TOUT/4; ++i) {
        float4 v; v.x=h[4*i+0]; v.y=h[4*i+1]; v.z=h[4*i+2]; v.w=h[4*i+3];
        po[i] = v;
    }

    float4 xv = xd4[n];
    float dg = fmaxf(xv.w, 1.0f);
    float inv = __builtin_amdgcn_rcpf(dg);
    out_x[(size_t)n*3+0] = coord[(size_t)n*3+0] + xv.x * inv;
    out_x[(size_t)n*3+1] = coord[(size_t)n*3+1] + xv.y * inv;
    out_x[(size_t)n*3+2] = coord[(size_t)n*3+2] + xv.z * inv;
}

extern "C" void kernel_launch(void* const* d_in, const int* in_sizes, int n_in,
                              void* d_out, int out_size, void* d_ws, size_t ws_size,
                              hipStream_t stream) {
    const float* node_feat = (const float*)d_in[0];
    const float* coord     = (const float*)d_in[1];
    const float* edge_feat = (const float*)d_in[2];
    const int*   src       = (const int*)d_in[3];
    const int*   dst       = (const int*)d_in[4];
    const float* We1 = (const float*)d_in[5];
    const float* be1 = (const float*)d_in[6];
    const float* We2 = (const float*)d_in[7];
    const float* be2 = (const float*)d_in[8];
    const float* Wn1 = (const float*)d_in[9];
    const float* bn1 = (const float*)d_in[10];
    const float* Wn2 = (const float*)d_in[11];
    const float* bn2 = (const float*)d_in[12];
    const float* Wc1 = (const float*)d_in[13];
    const float* bc1 = (const float*)d_in[14];
    const float* Wc2 = (const float*)d_in[15];

    int N = in_sizes[0] / TIN;
    int E = in_sizes[3];

    float* out_h = (float*)d_out;
    float* out_x = out_h + (size_t)N * TOUT;

    // workspace layout
    uint4*        recs    = (uint4*)d_ws;                              // N*MAXDEG*2 uint4 (32B/slot)
    unsigned int* node_bf = (unsigned int*)(recs + ((size_t)N << 6) * 2);
    float4*       coord4  = (float4*)(node_bf + (size_t)N * 16);
    float*        h_acc   = (float*)(coord4 + N);                      // N*32 f32
    float4*       xd4     = (float4*)(h_acc + (size_t)N * THID);       // N
    int*          cnt     = (int*)(xd4 + N);                           // N+1
    size_t need = (size_t)((char*)(cnt + N + 1) - (char*)d_ws);

    if (need <= ws_size) {
        prep_kernel<<<2048, 256, 0, stream>>>(node_feat, coord, node_bf, coord4, cnt, N);
        record_rank_kernel<<<(E + 255) / 256, 256, 0, stream>>>(
            src, dst, coord4, edge_feat, cnt, recs, E);
        int nchunks = (N + CHUNK - 1) / CHUNK;
        egnn_fused<<<(nchunks + 3) / 4, 256, 0, stream>>>(
            (const uint4*)node_bf, recs, cnt,
            We1, be1, We2, be2, Wc1, bc1, Wc2,
            (float4*)h_acc, xd4, N);
        ovf_fix_node<<<(N + 255) / 256, 256, 0, stream>>>(
            node_feat, coord, edge_feat, src, dst, cnt,
            We1, be1, We2, be2, Wc1, bc1, Wc2, h_acc, xd4, N, E);
        egnn_node<<<(N + 255) / 256, 256, 0, stream>>>(
            node_feat, coord, Wn1, bn1, Wn2, bn2,
            h_acc, xd4, out_h, out_x, N);
    } else {
        float* fh_acc = (float*)d_ws;
        float* fx_acc = fh_acc + (size_t)N * THID;   // [N][4]
        hipMemsetAsync(d_ws, 0, sizeof(float) * (size_t)N * (THID + 4), stream);
        egnn_edge_atomic<<<(E + 255) / 256, 256, 0, stream>>>(
            node_feat, coord, edge_feat, src, dst,
            We1, be1, We2, be2, Wc1, bc1, Wc2,
            fh_acc, fx_acc, E);
        egnn_node<<<(N + 255) / 256, 256, 0, stream>>>(
            node_feat, coord, Wn1, bn1, Wn2, bn2,
            fh_acc, (const float4*)fx_acc, out_h, out_x, N);
    }
}